// Round 3
// baseline (29.617 us; speedup 1.0000x reference)
//
#include <hip/hip_runtime.h>
#include <math.h>

// Problem constants
#define B   32
#define P   1024
#define DX  5
#define BP  (B * P)            // 32768 particles
#define LIKE_OFF (BP * DX)     // offset of `like` in flat d_out (163840)

// Dataflow (verified R0): new_state depends only on particles + pr1/2/3;
// like == 1/1024 exactly.
//
// R2 theory: R1's wave-uniform weight reads became SMEM (s_load) streams that
// serialize on conservative lgkmcnt(0) waits with only 1 wave/SIMD to hide
// them (~8us/wave stalls). Fix: force the weight stream onto the VMEM vector
// path (global_load_dwordx4 with immediate offsets), which the compiler
// software-pipelines with counted vmcnt. The "+v" empty-asm trick makes the
// base pointer per-lane (VGPR), defeating scalarization.

__device__ __forceinline__ float fast_tanh(float x) {
    x = fminf(fmaxf(x, -15.0f), 15.0f);
    float e = __expf(2.0f * x);
    return (e - 1.0f) / (e + 1.0f);
}

__global__ __launch_bounds__(128) void particle_kernel(
    const float* __restrict__ particles,   // (B*P, 5)
    const float* __restrict__ pr1_w,       // (2, 32)
    const float* __restrict__ pr1_b,       // (32,)
    const float* __restrict__ pr2_w,       // (32, 64)
    const float* __restrict__ pr2_b,       // (64,)
    const float* __restrict__ pr3_w,       // (64, 2)
    const float* __restrict__ pr3_b,       // (2,)
    float* __restrict__ out)               // [BP*5 new_state | BP like]
{
    const int idx = blockIdx.x * 128 + threadIdx.x;   // 0..BP-1

    // ---- Force vector (VMEM) path for all weight streams ----
    const float4* w1v = reinterpret_cast<const float4*>(pr1_w);   // 16 x float4
    const float4* b1v = reinterpret_cast<const float4*>(pr1_b);   // 8  x float4
    const float4* w2v = reinterpret_cast<const float4*>(pr2_w);   // 512x float4
    const float4* b2v = reinterpret_cast<const float4*>(pr2_b);   // 16 x float4
    const float4* w3v = reinterpret_cast<const float4*>(pr3_w);   // 32 x float4
    asm("" : "+v"(w1v));
    asm("" : "+v"(b1v));
    asm("" : "+v"(w2v));
    asm("" : "+v"(b2v));
    asm("" : "+v"(w3v));

    // Per-particle state: 5 consecutive floats
    const float* s = particles + idx * DX;
    const float s0 = s[0];
    const float s1 = s[1];
    const float s2 = s[2];
    const float v  = s[3];
    const float td = s[4];

    const float theta = s2 + td;
    const float x = fmaf(v, __sinf(theta), s0);
    const float y = fmaf(v, __cosf(theta), s1);

    // ---- Layer 1: din(2) @ (2,32) + b1, relu ----
    float h1[32];
#pragma unroll
    for (int j4 = 0; j4 < 8; ++j4) {
        float4 wa = w1v[j4];        // pr1_w[0][4j..4j+3]
        float4 wb = w1v[8 + j4];    // pr1_w[1][4j..4j+3]
        float4 bb = b1v[j4];
        h1[j4 * 4 + 0] = fmaxf(fmaf(v, wa.x, fmaf(td, wb.x, bb.x)), 0.0f);
        h1[j4 * 4 + 1] = fmaxf(fmaf(v, wa.y, fmaf(td, wb.y, bb.y)), 0.0f);
        h1[j4 * 4 + 2] = fmaxf(fmaf(v, wa.z, fmaf(td, wb.z, bb.z)), 0.0f);
        h1[j4 * 4 + 3] = fmaxf(fmaf(v, wa.w, fmaf(td, wb.w, bb.w)), 0.0f);
    }

    // ---- Layer 2: h1(32) @ (32,64) + b2, relu ----
    float4 acc[16];
#pragma unroll
    for (int j4 = 0; j4 < 16; ++j4) acc[j4] = b2v[j4];
#pragma unroll
    for (int k = 0; k < 32; ++k) {
        const float hk = h1[k];
#pragma unroll
        for (int j4 = 0; j4 < 16; ++j4) {
            float4 w = w2v[k * 16 + j4];
            acc[j4].x = fmaf(hk, w.x, acc[j4].x);
            acc[j4].y = fmaf(hk, w.y, acc[j4].y);
            acc[j4].z = fmaf(hk, w.z, acc[j4].z);
            acc[j4].w = fmaf(hk, w.w, acc[j4].w);
        }
    }

    // ---- Layer 3: relu(h2)(64) @ (64,2) + b3, tanh ----
    // w3v[j2] = {W3[2j2,0], W3[2j2,1], W3[2j2+1,0], W3[2j2+1,1]}
    float u0 = pr3_b[0];
    float u1 = pr3_b[1];
#pragma unroll
    for (int j4 = 0; j4 < 16; ++j4) {
        float4 h = acc[j4];
        h.x = fmaxf(h.x, 0.0f);
        h.y = fmaxf(h.y, 0.0f);
        h.z = fmaxf(h.z, 0.0f);
        h.w = fmaxf(h.w, 0.0f);
        float4 wA = w3v[j4 * 2 + 0];   // neurons 4j4, 4j4+1
        float4 wB = w3v[j4 * 2 + 1];   // neurons 4j4+2, 4j4+3
        u0 = fmaf(h.x, wA.x, u0); u1 = fmaf(h.x, wA.y, u1);
        u0 = fmaf(h.y, wA.z, u0); u1 = fmaf(h.y, wA.w, u1);
        u0 = fmaf(h.z, wB.x, u0); u1 = fmaf(h.z, wB.y, u1);
        u0 = fmaf(h.w, wB.z, u0); u1 = fmaf(h.w, wB.w, u1);
    }
    u0 = fast_tanh(u0);
    u1 = fast_tanh(u1);

    // new_state = [x, y, theta, v + u0, td + u1]
    float* o = out + idx * DX;
    o[0] = x;
    o[1] = y;
    o[2] = theta;
    o[3] = v + u0;
    o[4] = td + u1;

    // like = 1/P exactly
    out[LIKE_OFF + idx] = 1.0f / 1024.0f;
}

extern "C" void kernel_launch(void* const* d_in, const int* in_sizes, int n_in,
                              void* d_out, int out_size, void* d_ws, size_t ws_size,
                              hipStream_t stream) {
    const float* particles = (const float*)d_in[1];
    const float* pr1_w = (const float*)d_in[24];
    const float* pr1_b = (const float*)d_in[25];
    const float* pr2_w = (const float*)d_in[26];
    const float* pr2_b = (const float*)d_in[27];
    const float* pr3_w = (const float*)d_in[28];
    const float* pr3_b = (const float*)d_in[29];
    float* out = (float*)d_out;

    dim3 grid(BP / 128);   // 256 blocks -> 1 per CU
    dim3 block(128);
    particle_kernel<<<grid, block, 0, stream>>>(
        particles, pr1_w, pr1_b, pr2_w, pr2_b, pr3_w, pr3_b, out);
}

// Round 4
// 15.160 us; speedup vs baseline: 1.9536x; 1.9536x over previous
//
#include <hip/hip_runtime.h>
#include <math.h>

// Problem constants
#define B   32
#define P   1024
#define DX  5
#define BP  (B * P)            // 32768 particles
#define LIKE_OFF (BP * DX)     // offset of `like` in flat d_out (163840)

// Dataflow (verified R0): new_state depends only on particles + pr1/2/3;
// like == 1/1024 exactly.
//
// R3: weight-delivery redesign. All previous variants (LDS-broadcast 24us,
// SMEM 21us, per-lane VMEM 30us) redundantly streamed the full 8KB W2 to
// every consumer at <=1 wave/SIMD. Now: lane j owns W2 column j in 32 VGPRs
// (loaded once per wave, coalesced); a wave processes 8 particles serially.
// h1 (wave-uniform per particle) is broadcast through a 128B per-wave LDS
// slot (same-wave RAW -> no barrier). 64->2 layer via butterfly shuffle
// reduce. 4096 waves = 4 waves/SIMD on all 256 CUs.

#define PPW 8                  // particles per wave
#define NWAVES (BP / PPW)      // 4096 waves
#define BLOCKS (NWAVES / 4)    // 1024 blocks of 256 threads (4 waves)

__device__ __forceinline__ float fast_tanh(float x) {
    x = fminf(fmaxf(x, -15.0f), 15.0f);
    float e = __expf(2.0f * x);
    return (e - 1.0f) / (e + 1.0f);
}

__global__ __launch_bounds__(256, 4) void particle_kernel(
    const float* __restrict__ particles,   // (B*P, 5)
    const float* __restrict__ pr1_w,       // (2, 32)
    const float* __restrict__ pr1_b,       // (32,)
    const float* __restrict__ pr2_w,       // (32, 64) row-major
    const float* __restrict__ pr2_b,       // (64,)
    const float* __restrict__ pr3_w,       // (64, 2)
    const float* __restrict__ pr3_b,       // (2,)
    float* __restrict__ out)               // [BP*5 new_state | BP like]
{
    const int lane = threadIdx.x & 63;
    const int ws   = threadIdx.x >> 6;                    // wave slot in block
    const int wid  = blockIdx.x * 4 + ws;                 // global wave id

    // ---- One-time per-wave weight staging into VGPRs (all coalesced) ----
    float w2col[32];                       // W2[:, lane]
#pragma unroll
    for (int k = 0; k < 32; ++k) w2col[k] = pr2_w[k * 64 + lane];
    const float  b2j = pr2_b[lane];
    const float2 w3  = reinterpret_cast<const float2*>(pr3_w)[lane]; // W3[lane,:]
    float w1a = 0.0f, w1b = 0.0f, w1c = 0.0f;
    if (lane < 32) {                       // L1 weights for h1[lane]
        w1a = pr1_w[lane];
        w1b = pr1_w[32 + lane];
        w1c = pr1_b[lane];
    }
    const float b3a = pr3_b[0];
    const float b3b = pr3_b[1];

    // Per-wave h1 broadcast slot (same-wave write->read, no barrier needed)
    __shared__ __align__(16) float h1s[4][32];

    for (int p = 0; p < PPW; ++p) {
        const int idx = wid * PPW + p;     // particle index, 0..BP-1

        // Wave-uniform particle state (broadcast loads, L1-resident)
        const float* s = particles + idx * DX;
        const float s0 = s[0];
        const float s1 = s[1];
        const float s2 = s[2];
        const float v  = s[3];
        const float td = s[4];

        const float theta = s2 + td;
        const float x = fmaf(v, __sinf(theta), s0);
        const float y = fmaf(v, __cosf(theta), s1);

        // Layer 1: lane j<32 computes h1[j]; park in LDS for broadcast
        const float h1 = fmaxf(fmaf(v, w1a, fmaf(td, w1b, w1c)), 0.0f);
        if (lane < 32) h1s[ws][lane] = h1;

        // Layer 2: dot(h1, W2[:, lane]) via broadcast ds_read_b128
        float acc = b2j;
        const float4* h4 = reinterpret_cast<const float4*>(h1s[ws]);
#pragma unroll
        for (int k4 = 0; k4 < 8; ++k4) {
            const float4 h = h4[k4];
            acc = fmaf(h.x, w2col[k4 * 4 + 0], acc);
            acc = fmaf(h.y, w2col[k4 * 4 + 1], acc);
            acc = fmaf(h.z, w2col[k4 * 4 + 2], acc);
            acc = fmaf(h.w, w2col[k4 * 4 + 3], acc);
        }
        const float h2 = fmaxf(acc, 0.0f);

        // Layer 3 partials + 64-lane butterfly reduction
        float u0 = h2 * w3.x;
        float u1 = h2 * w3.y;
#pragma unroll
        for (int m = 1; m < 64; m <<= 1) {
            u0 += __shfl_xor(u0, m, 64);
            u1 += __shfl_xor(u1, m, 64);
        }
        u0 = fast_tanh(u0 + b3a);
        u1 = fast_tanh(u1 + b3b);

        // Single exec-masked store: lanes 0-4 -> new_state, lane 5 -> like
        if (lane < 6) {
            const float val = (lane == 0) ? x
                            : (lane == 1) ? y
                            : (lane == 2) ? theta
                            : (lane == 3) ? (v + u0)
                            : (lane == 4) ? (td + u1)
                            : (1.0f / 1024.0f);
            float* addr = (lane < 5) ? (out + idx * DX + lane)
                                     : (out + LIKE_OFF + idx);
            *addr = val;
        }
    }
}

extern "C" void kernel_launch(void* const* d_in, const int* in_sizes, int n_in,
                              void* d_out, int out_size, void* d_ws, size_t ws_size,
                              hipStream_t stream) {
    const float* particles = (const float*)d_in[1];
    const float* pr1_w = (const float*)d_in[24];
    const float* pr1_b = (const float*)d_in[25];
    const float* pr2_w = (const float*)d_in[26];
    const float* pr2_b = (const float*)d_in[27];
    const float* pr3_w = (const float*)d_in[28];
    const float* pr3_b = (const float*)d_in[29];
    float* out = (float*)d_out;

    dim3 grid(BLOCKS);    // 1024 blocks -> 4 waves/SIMD on all 256 CUs
    dim3 block(256);
    particle_kernel<<<grid, block, 0, stream>>>(
        particles, pr1_w, pr1_b, pr2_w, pr2_b, pr3_w, pr3_b, out);
}

// Round 5
// 13.150 us; speedup vs baseline: 2.2524x; 1.1529x over previous
//
#include <hip/hip_runtime.h>
#include <math.h>

// Problem constants
#define B   32
#define P   1024
#define DX  5
#define BP  (B * P)            // 32768 particles
#define LIKE_OFF (BP * DX)     // offset of `like` in flat d_out (163840)

// Dataflow (verified R0): new_state depends only on particles + pr1/2/3;
// like == 1/1024 exactly.
//
// R3 (15.2us): lane j owns W2 column j in VGPRs; 8 particles/wave.
// R4: kill exposed latency, not instruction count:
//   - particle states preloaded via readfirstlane-uniform base -> SMEM batch,
//     one drain before the loop (R3 re-loaded 5 floats per iteration through
//     VMEM broadcast with ~200cyc exposed each).
//   - phase-split: all h1 ds_writes (+ x/y/theta stores, which are MLP-free)
//     first, then all dot/reduce phases -> ds_read latency pipelines across
//     particles instead of RAW-stalling per iteration.
//   - parity-split reduction: butterfly on ONE value (masks 2..32), one tanh
//     per lane; lane0 stores v+t (t=tanh u0), lane1 stores td+t (t=tanh u1).
//   - like: single coalesced 8-lane store per wave.

#define PPW 8                  // particles per wave
#define NWAVES (BP / PPW)      // 4096 waves
#define BLOCKS (NWAVES / 4)    // 1024 blocks of 256 threads

__device__ __forceinline__ float fast_tanh(float x) {
    x = fminf(fmaxf(x, -15.0f), 15.0f);
    float e = __expf(2.0f * x);
    return (e - 1.0f) / (e + 1.0f);
}

__global__ __launch_bounds__(256, 4) void particle_kernel(
    const float* __restrict__ particles,   // (B*P, 5)
    const float* __restrict__ pr1_w,       // (2, 32)
    const float* __restrict__ pr1_b,       // (32,)
    const float* __restrict__ pr2_w,       // (32, 64) row-major
    const float* __restrict__ pr2_b,       // (64,)
    const float* __restrict__ pr3_w,       // (64, 2)
    const float* __restrict__ pr3_b,       // (2,)
    float* __restrict__ out)               // [BP*5 new_state | BP like]
{
    const int lane = threadIdx.x & 63;
    const int ws   = threadIdx.x >> 6;
    const int wid  = blockIdx.x * 4 + ws;

    // ---- Per-lane weight staging (issued together, single drain) ----
    float w2col[32];                        // W2[:, lane]
#pragma unroll
    for (int k = 0; k < 32; ++k) w2col[k] = pr2_w[k * 64 + lane];
    const float  b2j = pr2_b[lane];
    const float2 w3  = reinterpret_cast<const float2*>(pr3_w)[lane]; // W3[lane,:]
    float w1a = 0.0f, w1b = 0.0f, w1c = 0.0f;
    if (lane < 32) {
        w1a = pr1_w[lane];
        w1b = pr1_w[32 + lane];
        w1c = pr1_b[lane];
    }
    const float b3 = (lane & 1) ? pr3_b[1] : pr3_b[0];

    // ---- Scalar-preload all 8 particle states (40 floats) ----
    // readfirstlane certifies uniformity -> s_load batch into SGPRs,
    // one lgkmcnt drain, zero per-iteration load latency.
    const int pbase = __builtin_amdgcn_readfirstlane(wid * (PPW * DX));
    float ps[PPW * DX];
#pragma unroll
    for (int i = 0; i < PPW * DX; ++i) ps[i] = particles[pbase + i];

    __shared__ float h1s[4][PPW][32];      // 4KB

    // ---- Phase 1: h1 for all particles + MLP-free outputs ----
#pragma unroll
    for (int p = 0; p < PPW; ++p) {
        const float s0 = ps[p * 5 + 0];
        const float s1 = ps[p * 5 + 1];
        const float s2 = ps[p * 5 + 2];
        const float v  = ps[p * 5 + 3];
        const float td = ps[p * 5 + 4];
        const float theta = s2 + td;

        if (lane < 32)
            h1s[ws][p][lane] = fmaxf(fmaf(v, w1a, fmaf(td, w1b, w1c)), 0.0f);

        if (lane < 3) {
            const float val = (lane == 0) ? fmaf(v, __sinf(theta), s0)
                            : (lane == 1) ? fmaf(v, __cosf(theta), s1)
                            : theta;
            out[(wid * PPW + p) * DX + lane] = val;
        }
    }

    // like: one coalesced store per wave (8 particles)
    if (lane < PPW) out[LIKE_OFF + wid * PPW + lane] = 1.0f / 1024.0f;

    // ---- Phase 2: dot + reduce + tanh + store, per particle ----
#pragma unroll
    for (int p = 0; p < PPW; ++p) {
        const float4* h4 = reinterpret_cast<const float4*>(h1s[ws][p]);
        float acc = b2j;
#pragma unroll
        for (int k4 = 0; k4 < 8; ++k4) {
            const float4 h = h4[k4];
            acc = fmaf(h.x, w2col[k4 * 4 + 0], acc);
            acc = fmaf(h.y, w2col[k4 * 4 + 1], acc);
            acc = fmaf(h.z, w2col[k4 * 4 + 2], acc);
            acc = fmaf(h.w, w2col[k4 * 4 + 3], acc);
        }
        const float h2 = fmaxf(acc, 0.0f);

        // Layer 3 parity-split reduction: even lanes carry u0, odd carry u1
        const float a0 = h2 * w3.x;
        const float a1 = h2 * w3.y;
        const bool odd = (lane & 1);
        float mine   = odd ? a1 : a0;
        float theirs = odd ? a0 : a1;
        mine += __shfl_xor(theirs, 1, 64);
#pragma unroll
        for (int m = 2; m < 64; m <<= 1) mine += __shfl_xor(mine, m, 64);

        const float t = fast_tanh(mine + b3);   // lane0: tanh(u0), lane1: tanh(u1)

        if (lane < 2) {
            const float val = ((lane == 0) ? ps[p * 5 + 3] : ps[p * 5 + 4]) + t;
            out[(wid * PPW + p) * DX + 3 + lane] = val;
        }
    }
}

extern "C" void kernel_launch(void* const* d_in, const int* in_sizes, int n_in,
                              void* d_out, int out_size, void* d_ws, size_t ws_size,
                              hipStream_t stream) {
    const float* particles = (const float*)d_in[1];
    const float* pr1_w = (const float*)d_in[24];
    const float* pr1_b = (const float*)d_in[25];
    const float* pr2_w = (const float*)d_in[26];
    const float* pr2_b = (const float*)d_in[27];
    const float* pr3_w = (const float*)d_in[28];
    const float* pr3_b = (const float*)d_in[29];
    float* out = (float*)d_out;

    dim3 grid(BLOCKS);    // 1024 blocks -> 4 waves/SIMD on all 256 CUs
    dim3 block(256);
    particle_kernel<<<grid, block, 0, stream>>>(
        particles, pr1_w, pr1_b, pr2_w, pr2_b, pr3_w, pr3_b, out);
}

// Round 6
// 12.507 us; speedup vs baseline: 2.3680x; 1.0514x over previous
//
#include <hip/hip_runtime.h>
#include <math.h>

// Problem constants
#define B   32
#define P   1024
#define DX  5
#define BP  (B * P)            // 32768 particles
#define LIKE_OFF (BP * DX)     // offset of `like` in flat d_out (163840)

// Dataflow (verified R0): new_state depends only on particles + pr1/2/3;
// like == 1/1024 exactly.
//
// Ladder: R0 24.0 (LDS broadcast) -> R1 21.2 (SMEM) -> R2 29.6 (VMEM, FAIL)
// -> R3 15.2 (col-owner VGPR weights) -> R4 13.1 (phase split + s_load).
// Implied fixed floor ~10.5-11us (graph replay); kernel residual ~2-2.5us.
//
// R5: pair-processing. Two particles per wave concurrently (lane half h =
// particle parity, j = lane&31). Each lane owns W2 cols (2j, 2j+1) as float2
// -> per PAIR: 8 broadcast ds_read_b128 (2 addrs/instr, 128B apart = same
// banks, 2-way = free), 5-stage half-local shuffle reduce (parity-split:
// odd j carries u0, even j carries u1), one tanh pass, one sin+cos, one
// masked store. DS ops/particle 14 -> 6.5 (tests the LDS-pipe model).

#define PPW   8                // particles per wave
#define PAIRS (PPW / 2)
#define NWAVES (BP / PPW)      // 4096 waves
#define BLOCKS (NWAVES / 4)    // 1024 blocks of 256 threads

__device__ __forceinline__ float fast_tanh(float x) {
    x = fminf(fmaxf(x, -15.0f), 15.0f);
    float e = __expf(2.0f * x);
    return (e - 1.0f) / (e + 1.0f);
}

__global__ __launch_bounds__(256, 4) void particle_kernel(
    const float* __restrict__ particles,   // (B*P, 5)
    const float* __restrict__ pr1_w,       // (2, 32)
    const float* __restrict__ pr1_b,       // (32,)
    const float* __restrict__ pr2_w,       // (32, 64) row-major
    const float* __restrict__ pr2_b,       // (64,)
    const float* __restrict__ pr3_w,       // (64, 2)
    const float* __restrict__ pr3_b,       // (2,)
    float* __restrict__ out)               // [BP*5 new_state | BP like]
{
    const int lane = threadIdx.x & 63;
    const int ws   = threadIdx.x >> 6;
    const int wid  = blockIdx.x * 4 + ws;
    const int h    = lane >> 5;            // which particle of the pair
    const int j    = lane & 31;            // col-pair owner / h1 col / field id

    // ---- Weight staging: lane owns W2 cols (2j, 2j+1). Both halves load
    // identical addresses (L1 broadcast); float2 = 8B/lane coalesced. ----
    float2 w2[32];
#pragma unroll
    for (int k = 0; k < 32; ++k)
        w2[k] = reinterpret_cast<const float2*>(pr2_w + k * 64)[j];
    const float2 b2 = reinterpret_cast<const float2*>(pr2_b)[j];
    const float4 w3 = reinterpret_cast<const float4*>(pr3_w)[j]; // rows 2j,2j+1
    const float  w1a = pr1_w[j], w1b = pr1_w[32 + j], w1c = pr1_b[j];
    const float  b3a = pr3_b[0], b3b = pr3_b[1];

    // ---- Scalar-preload all 8 particle states (uniform base -> s_load) ----
    const int pbase = __builtin_amdgcn_readfirstlane(wid * (PPW * DX));
    float ps[PPW * DX];
#pragma unroll
    for (int i = 0; i < PPW * DX; ++i) ps[i] = particles[pbase + i];

    __shared__ float h1s[4][PPW][32];      // 4KB

    // like: one coalesced store per wave
    if (lane < PPW) out[LIKE_OFF + wid * PPW + lane] = 1.0f / 1024.0f;

    // ---- Phase 1: h1 for all 8 particles (lane -> particle pr*2+h, col j) ----
#pragma unroll
    for (int pr = 0; pr < PAIRS; ++pr) {
        const float v  = h ? ps[(pr * 2 + 1) * DX + 3] : ps[(pr * 2 + 0) * DX + 3];
        const float td = h ? ps[(pr * 2 + 1) * DX + 4] : ps[(pr * 2 + 0) * DX + 4];
        h1s[ws][pr * 2 + h][j] = fmaxf(fmaf(v, w1a, fmaf(td, w1b, w1c)), 0.0f);
    }

    // ---- Phase 2: per pair -> dot, half-local reduce, tanh, one store ----
#pragma unroll
    for (int pr = 0; pr < PAIRS; ++pr) {
        const float4* h4 = reinterpret_cast<const float4*>(h1s[ws][pr * 2 + h]);
        float a0 = b2.x, a1 = b2.y;
#pragma unroll
        for (int k4 = 0; k4 < 8; ++k4) {
            const float4 hv = h4[k4];
            a0 = fmaf(hv.x, w2[k4 * 4 + 0].x, a0); a1 = fmaf(hv.x, w2[k4 * 4 + 0].y, a1);
            a0 = fmaf(hv.y, w2[k4 * 4 + 1].x, a0); a1 = fmaf(hv.y, w2[k4 * 4 + 1].y, a1);
            a0 = fmaf(hv.z, w2[k4 * 4 + 2].x, a0); a1 = fmaf(hv.z, w2[k4 * 4 + 2].y, a1);
            a0 = fmaf(hv.w, w2[k4 * 4 + 3].x, a0); a1 = fmaf(hv.w, w2[k4 * 4 + 3].y, a1);
        }
        const float h20 = fmaxf(a0, 0.0f);
        const float h21 = fmaxf(a1, 0.0f);

        // Layer-3 partials: rows 2j (w3.x,.y) and 2j+1 (w3.z,.w)
        float u0p = fmaf(h20, w3.x, h21 * w3.z);
        float u1p = fmaf(h20, w3.y, h21 * w3.w);

        // Parity-split reduce within each 32-lane half: odd j -> u0, even -> u1
        const bool odd = (j & 1);
        float mine   = odd ? u0p : u1p;
        float theirs = odd ? u1p : u0p;
        mine += __shfl_xor(theirs, 1, 64);
        mine += __shfl_xor(mine, 2, 64);
        mine += __shfl_xor(mine, 4, 64);
        mine += __shfl_xor(mine, 8, 64);
        mine += __shfl_xor(mine, 16, 64);
        // odd j: u0 sum; even j: u1 sum (half-local = per-particle)

        const float t = fast_tanh(mine + (odd ? b3a : b3b));
        // j=3 (odd)  -> t = tanh(u0) = t0 for field 3 (v + t0)
        // j=4 (even) -> t = tanh(u1) = t1 for field 4 (td + t1)

        // Outputs: one masked store, lanes 0-4 = particle A, 32-36 = B
        const float s0 = h ? ps[(pr * 2 + 1) * DX + 0] : ps[(pr * 2 + 0) * DX + 0];
        const float s1 = h ? ps[(pr * 2 + 1) * DX + 1] : ps[(pr * 2 + 0) * DX + 1];
        const float s2 = h ? ps[(pr * 2 + 1) * DX + 2] : ps[(pr * 2 + 0) * DX + 2];
        const float v  = h ? ps[(pr * 2 + 1) * DX + 3] : ps[(pr * 2 + 0) * DX + 3];
        const float td = h ? ps[(pr * 2 + 1) * DX + 4] : ps[(pr * 2 + 0) * DX + 4];
        const float theta = s2 + td;
        const float x = fmaf(v, __sinf(theta), s0);   // one sin/cos per PAIR
        const float y = fmaf(v, __cosf(theta), s1);

        const float val = (j == 0) ? x
                        : (j == 1) ? y
                        : (j == 2) ? theta
                        : (j == 3) ? (v + t)
                        :            (td + t);
        if (j < DX)
            out[(wid * PPW + pr * 2 + h) * DX + j] = val;
    }
}

extern "C" void kernel_launch(void* const* d_in, const int* in_sizes, int n_in,
                              void* d_out, int out_size, void* d_ws, size_t ws_size,
                              hipStream_t stream) {
    const float* particles = (const float*)d_in[1];
    const float* pr1_w = (const float*)d_in[24];
    const float* pr1_b = (const float*)d_in[25];
    const float* pr2_w = (const float*)d_in[26];
    const float* pr2_b = (const float*)d_in[27];
    const float* pr3_w = (const float*)d_in[28];
    const float* pr3_b = (const float*)d_in[29];
    float* out = (float*)d_out;

    dim3 grid(BLOCKS);    // 1024 blocks -> 4 waves/SIMD on all 256 CUs
    dim3 block(256);
    particle_kernel<<<grid, block, 0, stream>>>(
        particles, pr1_w, pr1_b, pr2_w, pr2_b, pr3_w, pr3_b, out);
}

// Round 7
// 12.352 us; speedup vs baseline: 2.3977x; 1.0125x over previous
//
#include <hip/hip_runtime.h>
#include <math.h>

// Problem constants
#define B   32
#define P   1024
#define DX  5
#define BP  (B * P)            // 32768 particles
#define LIKE_OFF (BP * DX)     // offset of `like` in flat d_out (163840)

// Dataflow (verified R0): new_state depends only on particles + pr1/2/3;
// like == 1/1024 exactly.
//
// Ladder: R0 24.0 -> R1 21.2 -> R2 29.6(FAIL) -> R3 15.2 -> R4 13.1 ->
// R5 12.5 (pair processing). Residual model: ~10.6us replay floor +
// ~1.9us kernel, instruction-issue bound (~560 instr/wave, half scalar FMA).
//
// R6: v_pk_fma_f32 via k-parity packing. Lane j owns W2 cols (2j,2j+1)
// stored COLUMN-major as k-pair float2s; h1 k-pairs fall out of the
// ds_read_b128 float4 ({x,y},{z,w} even-aligned). Layer-2 dot becomes
// 32 pk_fma + 4 horizontal adds per pair (was 64 scalar fma). Clamp-free
// tanh (saturates via rcp(inf)=0). ~-130 instr/wave.

#define PPW   8                // particles per wave
#define PAIRS (PPW / 2)
#define NWAVES (BP / PPW)      // 4096 waves
#define BLOCKS (NWAVES / 4)    // 1024 blocks of 256 threads

typedef float v2f __attribute__((ext_vector_type(2)));

__device__ __forceinline__ float fast_tanh(float x) {
    // 1 - 2/(e^{2x}+1); x->+inf: rcp(inf)=0 -> 1; x->-inf: rcp(1)=1 -> -1.
    const float d = __expf(2.0f * x) + 1.0f;
    return fmaf(-2.0f, __builtin_amdgcn_rcpf(d), 1.0f);
}

__global__ __launch_bounds__(256, 4) void particle_kernel(
    const float* __restrict__ particles,   // (B*P, 5)
    const float* __restrict__ pr1_w,       // (2, 32)
    const float* __restrict__ pr1_b,       // (32,)
    const float* __restrict__ pr2_w,       // (32, 64) row-major
    const float* __restrict__ pr2_b,       // (64,)
    const float* __restrict__ pr3_w,       // (64, 2)
    const float* __restrict__ pr3_b,       // (2,)
    float* __restrict__ out)               // [BP*5 new_state | BP like]
{
    const int lane = threadIdx.x & 63;
    const int ws   = threadIdx.x >> 6;
    const int wid  = blockIdx.x * 4 + ws;
    const int h    = lane >> 5;            // which particle of the pair
    const int j    = lane & 31;            // col-pair owner / h1 col / field id

    // ---- Weight staging: k-pair column-major so pk_fma needs no splat ----
    // wA[i] = {W2[2i][2j],   W2[2i+1][2j]}   (col c0 = 2j)
    // wB[i] = {W2[2i][2j+1], W2[2i+1][2j+1]} (col c1 = 2j+1)
    v2f wA[16], wB[16];
    const int c0 = 2 * j;
#pragma unroll
    for (int i = 0; i < 16; ++i) {
        wA[i].x = pr2_w[(2 * i) * 64 + c0];
        wA[i].y = pr2_w[(2 * i + 1) * 64 + c0];
        wB[i].x = pr2_w[(2 * i) * 64 + c0 + 1];
        wB[i].y = pr2_w[(2 * i + 1) * 64 + c0 + 1];
    }
    const float2 b2 = reinterpret_cast<const float2*>(pr2_b)[j];
    const float4 w3 = reinterpret_cast<const float4*>(pr3_w)[j]; // rows 2j,2j+1
    const float  w1a = pr1_w[j], w1b = pr1_w[32 + j], w1c = pr1_b[j];
    const float  b3a = pr3_b[0], b3b = pr3_b[1];

    // ---- Scalar-preload all 8 particle states (uniform base -> s_load) ----
    const int pbase = __builtin_amdgcn_readfirstlane(wid * (PPW * DX));
    float ps[PPW * DX];
#pragma unroll
    for (int i = 0; i < PPW * DX; ++i) ps[i] = particles[pbase + i];

    __shared__ __align__(16) float h1s[4][PPW][32];   // 4KB

    // like: one coalesced store per wave
    if (lane < PPW) out[LIKE_OFF + wid * PPW + lane] = 1.0f / 1024.0f;

    // ---- Phase 1: h1 for all 8 particles (lane -> particle pr*2+h, col j) ----
#pragma unroll
    for (int pr = 0; pr < PAIRS; ++pr) {
        const float v  = h ? ps[(pr * 2 + 1) * DX + 3] : ps[(pr * 2 + 0) * DX + 3];
        const float td = h ? ps[(pr * 2 + 1) * DX + 4] : ps[(pr * 2 + 0) * DX + 4];
        h1s[ws][pr * 2 + h][j] = fmaxf(fmaf(v, w1a, fmaf(td, w1b, w1c)), 0.0f);
    }

    // ---- Phase 2: per pair -> packed dot, half-local reduce, tanh, store ----
#pragma unroll
    for (int pr = 0; pr < PAIRS; ++pr) {
        const float4* h4 = reinterpret_cast<const float4*>(h1s[ws][pr * 2 + h]);
        v2f acc0 = {b2.x, 0.0f};
        v2f acc1 = {b2.y, 0.0f};
#pragma unroll
        for (int k4 = 0; k4 < 8; ++k4) {
            const float4 hv = h4[k4];
            const v2f lo = {hv.x, hv.y};
            const v2f hi = {hv.z, hv.w};
            acc0 = __builtin_elementwise_fma(lo, wA[2 * k4 + 0], acc0);
            acc1 = __builtin_elementwise_fma(lo, wB[2 * k4 + 0], acc1);
            acc0 = __builtin_elementwise_fma(hi, wA[2 * k4 + 1], acc0);
            acc1 = __builtin_elementwise_fma(hi, wB[2 * k4 + 1], acc1);
        }
        const float h20 = fmaxf(acc0.x + acc0.y, 0.0f);   // h2[2j]
        const float h21 = fmaxf(acc1.x + acc1.y, 0.0f);   // h2[2j+1]

        // Layer-3 partials: rows 2j (w3.x,.y) and 2j+1 (w3.z,.w)
        const float u0p = fmaf(h20, w3.x, h21 * w3.z);
        const float u1p = fmaf(h20, w3.y, h21 * w3.w);

        // Parity-split reduce within each 32-lane half: odd j -> u0, even -> u1
        const bool odd = (j & 1);
        float mine   = odd ? u0p : u1p;
        float theirs = odd ? u1p : u0p;
        mine += __shfl_xor(theirs, 1, 64);
        mine += __shfl_xor(mine, 2, 64);
        mine += __shfl_xor(mine, 4, 64);
        mine += __shfl_xor(mine, 8, 64);
        mine += __shfl_xor(mine, 16, 64);

        const float t = fast_tanh(mine + (odd ? b3a : b3b));
        // j=3 (odd)  -> t = tanh(u0) for field 3 (v + t0)
        // j=4 (even) -> t = tanh(u1) for field 4 (td + t1)

        // Outputs: one masked store, lanes 0-4 = particle A, 32-36 = B
        const float s0 = h ? ps[(pr * 2 + 1) * DX + 0] : ps[(pr * 2 + 0) * DX + 0];
        const float s1 = h ? ps[(pr * 2 + 1) * DX + 1] : ps[(pr * 2 + 0) * DX + 1];
        const float s2 = h ? ps[(pr * 2 + 1) * DX + 2] : ps[(pr * 2 + 0) * DX + 2];
        const float v  = h ? ps[(pr * 2 + 1) * DX + 3] : ps[(pr * 2 + 0) * DX + 3];
        const float td = h ? ps[(pr * 2 + 1) * DX + 4] : ps[(pr * 2 + 0) * DX + 4];
        const float theta = s2 + td;
        const float x = fmaf(v, __sinf(theta), s0);
        const float y = fmaf(v, __cosf(theta), s1);

        const float val = (j == 0) ? x
                        : (j == 1) ? y
                        : (j == 2) ? theta
                        : (j == 3) ? (v + t)
                        :            (td + t);
        if (j < DX)
            out[(wid * PPW + pr * 2 + h) * DX + j] = val;
    }
}

extern "C" void kernel_launch(void* const* d_in, const int* in_sizes, int n_in,
                              void* d_out, int out_size, void* d_ws, size_t ws_size,
                              hipStream_t stream) {
    const float* particles = (const float*)d_in[1];
    const float* pr1_w = (const float*)d_in[24];
    const float* pr1_b = (const float*)d_in[25];
    const float* pr2_w = (const float*)d_in[26];
    const float* pr2_b = (const float*)d_in[27];
    const float* pr3_w = (const float*)d_in[28];
    const float* pr3_b = (const float*)d_in[29];
    float* out = (float*)d_out;

    dim3 grid(BLOCKS);    // 1024 blocks -> 4 waves/SIMD on all 256 CUs
    dim3 block(256);
    particle_kernel<<<grid, block, 0, stream>>>(
        particles, pr1_w, pr1_b, pr2_w, pr2_b, pr3_w, pr3_b, out);
}